// Round 1
// baseline (1100.989 us; speedup 1.0000x reference)
//
#include <hip/hip_runtime.h>

// spatialAttentionScaledGCN — MI355X MFMA version.
// B=8, N=512, T=12, F=32, O=64. All I/O fp32.
// Per (b,t): S = X_t·X_tᵀ·inv_f  (mfma 16x16x32_f16, K=32=F, no K-loop),
// row-softmax over n (cross-wave stats via 2KB LDS, 1 barrier/chunk),
// W = sa·inv_f·phase (fp16, in C-layout regs == A-layout of Wᵀ for K=16 MFMA),
// x_pred += Wᵀ·X_prev (mfma 16x16x16f16), atomic-reduced over m-splits.
// Phase pre-permuted to MFMA lane order as fp16 (coalesced dwordx2 loads).
// R1: MT 4->8 (704/768 blocks, ~2.75 blocks/CU) + prefetch phase/adj/bp
//     registers BEFORE the softmax/barrier so L3/HBM latency hides under
//     the shuffle chains and the barrier's vmcnt drain.

#define B_ 8
#define N_ 512
#define T_ 12
#define F_ 32
#define O_ 64
#define MT 8                    // m-splits per (b,t); block owns 64 m-rows
#define NW 8                    // waves per block (512 threads)

typedef unsigned int uint_t;
typedef unsigned short ushort_t;
typedef _Float16 f16_t;
typedef _Float16 f16x4 __attribute__((ext_vector_type(4)));
typedef _Float16 f16x8 __attribute__((ext_vector_type(8)));
typedef float f32x4 __attribute__((ext_vector_type(4)));

__device__ __forceinline__ void atomAddF(float* p, float v) {
    __hip_atomic_fetch_add(p, v, __ATOMIC_RELAXED, __HIP_MEMORY_SCOPE_AGENT);
}
__device__ __forceinline__ int xidx(int b, int n, int t, int f) {
    return ((b * N_ + n) * T_ + t) * F_ + f;
}
// load 8 consecutive fp32, convert to packed f16x8 (one MFMA A/B frag quarter)
__device__ __forceinline__ f16x8 load_frag8(const float* p) {
    float4 a = *reinterpret_cast<const float4*>(p);
    float4 b = *reinterpret_cast<const float4*>(p + 4);
    f16x8 r;
    r[0] = (f16_t)a.x; r[1] = (f16_t)a.y; r[2] = (f16_t)a.z; r[3] = (f16_t)a.w;
    r[4] = (f16_t)b.x; r[5] = (f16_t)b.y; r[6] = (f16_t)b.z; r[7] = (f16_t)b.w;
    return r;
}
union U2H4 { uint2 u; f16x4 h; };

// ---------------------------------------------------------------------------
// Permute one 512x512 fp32 slice into MFMA-lane-order fp16:
// dst halves h = ((mc*32 + nt)*256) + quad*64 + col*4 + j  <=  src[mc*16+quad*4+j][nt*16+col]
// so a consuming lane l=quad*16+col reads its 4 halves with ONE dwordx2.
__global__ __launch_bounds__(256)
void permute_kernel(const float* __restrict__ src, ushort_t* __restrict__ dst)
{
    __shared__ float Lp[16][516];
    const int tid = threadIdx.x;
    const int mc  = blockIdx.x;               // 0..31 row-chunk
    const int s   = blockIdx.y;               // slice (b*12+t for phase; 0 for adj)
    src += (size_t)s * N_ * N_ + (size_t)mc * 16 * N_;
    uint_t* dstu = (uint_t*)dst + (size_t)s * 131072 + (size_t)mc * 4096;

    #pragma unroll
    for (int k = 0; k < 32; ++k) {
        int idx = tid + 256 * k;              // 0..8191
        Lp[idx >> 9][idx & 511] = src[idx];
    }
    __syncthreads();
    #pragma unroll
    for (int k = 0; k < 16; ++k) {
        int u    = tid + 256 * k;             // u32 index 0..4095
        int nt   = u >> 7;
        int r    = u & 127;
        int quad = r >> 5;
        int cl   = (r >> 1) & 15;
        int m0   = quad * 4 + (r & 1) * 2;
        int n    = nt * 16 + cl;
        union { f16_t h[2]; uint_t i; } pk;
        pk.h[0] = (f16_t)Lp[m0][n];
        pk.h[1] = (f16_t)Lp[m0 + 1][n];
        dstu[u] = pk.i;
    }
}

// ---------------------------------------------------------------------------
// One Jacobi iteration step for all (b, t>=1); block = (mt, t-1, b), 512 thr.
// FINAL=1: weight *= adj, Xp = X_t (same t), plain atomic to agg (no mask).
template <int FINAL>
__global__ __launch_bounds__(512)
void gcn_kernel(const float* __restrict__ x0,
                const float* __restrict__ xcur,
                float* __restrict__ dst,            // xnext or agg (pre-zeroed)
                const ushort_t* __restrict__ phase_h,
                const ushort_t* __restrict__ adj_h,
                const float* __restrict__ mask)
{
    __shared__ float2 st[2][NW][16];

    const int tid  = threadIdx.x;
    const int w    = tid >> 6;
    const int l    = tid & 63;
    const int quad = l >> 4;
    const int col  = l & 15;
    const int mt   = blockIdx.x;
    const int t    = FINAL ? blockIdx.y : blockIdx.y + 1;
    const int b    = blockIdx.z;
    const int nt0  = w * 4;                  // wave owns n-tiles nt0..nt0+3
    const float inv_f = 0.17677669529663687f;

    const float* xs     = (FINAL && t == 0) ? x0 : xcur;     // X_t source
    const float* xp_src = FINAL ? xs : ((t == 1) ? x0 : xcur); // pred operand
    const int    tp     = FINAL ? t : t - 1;

    // score B-frags for this wave's 4 n-tiles (fixed across chunks)
    f16x8 bf[4];
    #pragma unroll
    for (int i = 0; i < 4; ++i)
        bf[i] = load_frag8(&xs[xidx(b, (nt0 + i) * 16 + col, t, quad * 8)]);

    f32x4 acc[4][2];
    #pragma unroll
    for (int i = 0; i < 4; ++i) {
        acc[i][0] = (f32x4){0.f, 0.f, 0.f, 0.f};
        acc[i][1] = (f32x4){0.f, 0.f, 0.f, 0.f};
    }

    const uint_t* phu = (const uint_t*)phase_h + (size_t)(b * T_ + t) * 131072;
    const uint_t* adu = (const uint_t*)adj_h;

    for (int c = 0; c < 512 / (MT * 16); ++c) {   // 4 chunks of 16 m-rows
        const int mb = mt * (N_ / MT) + c * 16;
        const int mc = mb >> 4;                   // global chunk index

        // ---- issue ALL global loads for this chunk up front so their
        //      latency hides under the softmax shuffle chains + barrier ----
        f16x8 af = load_frag8(&xs[xidx(b, mb + col, t, quad * 8)]);

        U2H4 ph[4], aj[4];
        #pragma unroll
        for (int i = 0; i < 4; ++i) {
            ph[i].u = *(const uint2*)(phu + (size_t)mc * 4096 + (nt0 + i) * 128 + l * 2);
            if (FINAL)
                aj[i].u = *(const uint2*)(adu + (size_t)mc * 4096 + (nt0 + i) * 128 + l * 2);
        }
        // pred B-frags: Xp[m_local][f], K=16 layout k=quad*4+j
        f16x4 bp[2];
        #pragma unroll
        for (int ft = 0; ft < 2; ++ft)
            #pragma unroll
            for (int j = 0; j < 4; ++j)
                bp[ft][j] = (f16_t)xp_src[xidx(b, mb + quad * 4 + j, tp, ft * 16 + col)];

        // ---- scores: S[16 x 4*16] for this m-chunk ----
        f32x4 s4[4];
        #pragma unroll
        for (int i = 0; i < 4; ++i) {
            s4[i] = __builtin_amdgcn_mfma_f32_16x16x32_f16(
                        af, bf[i], (f32x4){0.f, 0.f, 0.f, 0.f}, 0, 0, 0);
        }
        // ---- wave-local softmax stats (rows m = quad*4+v, cols = 64 n) ----
        float mxw[4], sw[4], e[4][4];
        #pragma unroll
        for (int v = 0; v < 4; ++v) {
            #pragma unroll
            for (int i = 0; i < 4; ++i) s4[i][v] *= inv_f;
            mxw[v] = fmaxf(fmaxf(s4[0][v], s4[1][v]), fmaxf(s4[2][v], s4[3][v]));
        }
        #pragma unroll
        for (int d = 1; d < 16; d <<= 1)
            #pragma unroll
            for (int v = 0; v < 4; ++v)
                mxw[v] = fmaxf(mxw[v], __shfl_xor(mxw[v], d, 64));
        #pragma unroll
        for (int v = 0; v < 4; ++v) {
            #pragma unroll
            for (int i = 0; i < 4; ++i) e[i][v] = __expf(s4[i][v] - mxw[v]);
            sw[v] = (e[0][v] + e[1][v]) + (e[2][v] + e[3][v]);
        }
        #pragma unroll
        for (int d = 1; d < 16; d <<= 1)
            #pragma unroll
            for (int v = 0; v < 4; ++v)
                sw[v] += __shfl_xor(sw[v], d, 64);

        // ---- cross-wave combine via 2KB LDS (ping-pong, 1 barrier) ----
        const int buf = c & 1;
        if (col < 4) {
            float mv = (col == 0) ? mxw[0] : (col == 1) ? mxw[1] : (col == 2) ? mxw[2] : mxw[3];
            float sv = (col == 0) ? sw[0]  : (col == 1) ? sw[1]  : (col == 2) ? sw[2]  : sw[3];
            st[buf][w][quad * 4 + col] = make_float2(mv, sv);
        }
        __syncthreads();
        {
            const int row = l >> 2, wp = l & 3;
            float2 p0 = st[buf][2 * wp][row];
            float2 p1 = st[buf][2 * wp + 1][row];
            float M = fmaxf(p0.x, p1.x);
            float S = p0.y * __expf(p0.x - M) + p1.y * __expf(p1.x - M);
            #pragma unroll
            for (int d = 1; d < 4; d <<= 1) {
                float Mo = __shfl_xor(M, d, 64), So = __shfl_xor(S, d, 64);
                float Mn = fmaxf(M, Mo);
                S = S * __expf(M - Mn) + So * __expf(Mo - Mn);
                M = Mn;
            }
            #pragma unroll
            for (int v = 0; v < 4; ++v) {
                float Mr = __shfl(M, quad * 16 + v * 4, 64);
                float Sr = __shfl(S, quad * 16 + v * 4, 64);
                // beta = exp(local_max - global_max) * inv_f / global_sum
                mxw[v] = __expf(mxw[v] - Mr) * inv_f / Sr;   // reuse mxw as beta
            }
        }

        // ---- W = e*beta*phase(*adj), C-layout == A-layout of W^T; pred MFMA ----
        #pragma unroll
        for (int i = 0; i < 4; ++i) {
            f16x4 wf;
            if (FINAL) {
                #pragma unroll
                for (int v = 0; v < 4; ++v)
                    wf[v] = (f16_t)(e[i][v] * mxw[v] * (float)ph[i].h[v] * (float)aj[i].h[v]);
            } else {
                #pragma unroll
                for (int v = 0; v < 4; ++v)
                    wf[v] = (f16_t)(e[i][v] * mxw[v] * (float)ph[i].h[v]);
            }
            #pragma unroll
            for (int ft = 0; ft < 2; ++ft)
                acc[i][ft] = __builtin_amdgcn_mfma_f32_16x16x16f16(wf, bp[ft], acc[i][ft], 0, 0, 0);
        }
    }

    // ---- epilogue: atomic-reduce partial x_pred / agg ----
    #pragma unroll
    for (int i = 0; i < 4; ++i) {
        #pragma unroll
        for (int v = 0; v < 4; ++v) {
            const int n = (nt0 + i) * 16 + quad * 4 + v;
            if (FINAL) {
                float* d0 = &dst[((b * T_ + t) * N_ + n) * F_ + col];
                atomAddF(d0, acc[i][0][v]);
                atomAddF(d0 + 16, acc[i][1][v]);
            } else if (mask[n] == 0.f) {
                atomAddF(&dst[xidx(b, n, t, col)], acc[i][0][v]);
                atomAddF(&dst[xidx(b, n, t, 16 + col)], acc[i][1][v]);
            }
        }
    }
    if (!FINAL && mt == 0) {   // masked passthrough, single writer
        for (int p = tid; p < N_ * F_; p += 512) {
            int n = p >> 5, f = p & 31;
            if (mask[n] != 0.f) dst[xidx(b, n, t, f)] = xcur[xidx(b, n, t, f)];
        }
    }
}

// out[b,n,t,o] = relu(sum_f agg[b,t,n,f] * theta[f,o])
__global__ __launch_bounds__(256)
void proj_kernel(const float* __restrict__ agg, const float* __restrict__ theta,
                 float* __restrict__ out)
{
    __shared__ float th[F_ * O_];
    int tid = threadIdx.x;
    #pragma unroll
    for (int p = 0; p < 8; ++p) th[tid + 256 * p] = theta[tid + 256 * p];
    __syncthreads();
    int g  = blockIdx.x * 256 + tid;           // ((b*N+n)*T+t)*O+o
    int o  = g & 63;
    int r  = g >> 6;
    int tt = r % T_;
    int r2 = r / T_;
    int n  = r2 & 511;
    int b  = r2 >> 9;
    const float* a = &agg[((b * T_ + tt) * N_ + n) * F_];
    float s = 0.f;
    #pragma unroll
    for (int f = 0; f < F_; ++f) s += a[f] * th[f * O_ + o];
    out[g] = fmaxf(s, 0.f);
}

extern "C" void kernel_launch(void* const* d_in, const int* in_sizes, int n_in,
                              void* d_out, int out_size, void* d_ws, size_t ws_size,
                              hipStream_t stream)
{
    const float* x     = (const float*)d_in[0];
    const float* phase = (const float*)d_in[1];
    const float* adj   = (const float*)d_in[2];
    const float* mask  = (const float*)d_in[3];
    const float* theta = (const float*)d_in[4];
    float* out = (float*)d_out;

    const size_t XE = (size_t)B_ * N_ * T_ * F_;       // 1,572,864 floats
    float*    xA      = (float*)d_ws;                  //  6.3 MB
    float*    xB      = xA + XE;                       //  6.3 MB
    float*    agg     = xB + XE;                       //  6.3 MB
    ushort_t* phase_h = (ushort_t*)(agg + XE);         // 50.3 MB (96 slices, f16 permuted)
    ushort_t* adj_h   = phase_h + (size_t)96 * N_ * N_; // 0.5 MB

    permute_kernel<<<dim3(32, 96), 256, 0, stream>>>(phase, phase_h);
    permute_kernel<<<dim3(32, 1), 256, 0, stream>>>(adj, adj_h);

    const float* cur = x;
    float* bufs[2] = { xA, xB };
    for (int i = 0; i < T_ - 1; ++i) {                 // 11 Jacobi iterations
        float* nxt = bufs[i & 1];
        hipMemsetAsync(nxt, 0, XE * sizeof(float), stream);
        gcn_kernel<0><<<dim3(MT, T_ - 1, B_), 512, 0, stream>>>(
            x, cur, nxt, phase_h, adj_h, mask);
        cur = nxt;
    }
    hipMemsetAsync(agg, 0, XE * sizeof(float), stream);
    gcn_kernel<1><<<dim3(MT, T_, B_), 512, 0, stream>>>(
        x, cur, agg, phase_h, adj_h, mask);
    proj_kernel<<<(B_ * N_ * T_ * O_) / 256, 256, 0, stream>>>(agg, theta, out);
}

// Round 2
// 1061.129 us; speedup vs baseline: 1.0376x; 1.0376x over previous
//
#include <hip/hip_runtime.h>

// spatialAttentionScaledGCN — MI355X MFMA version.
// B=8, N=512, T=12, F=32, O=64. All I/O fp32.
// Per (b,t): S = X_t·X_tᵀ·inv_f  (mfma 16x16x32_f16, K=32=F, no K-loop),
// row-softmax over n (cross-wave stats via 2KB LDS, 1 barrier/chunk),
// W = sa·inv_f·phase (fp16, in C-layout regs == A-layout of Wᵀ for K=16 MFMA),
// x_pred += Wᵀ·X_prev (mfma 16x16x16f16).
// R2: MT=1 — one block owns the FULL m-sum for a (b,t) pair, accumulated in
//     registers across 32 chunks. Eliminates ALL agent-scope atomics (R0/R1
//     showed time scaled with atomic fabric-RMW traffic, not block count),
//     all 12 memset dispatches, and the masked-passthrough pass (epilogue
//     does a mask?xcur:acc select with exactly-once plain stores).
//     Grid = (1, T-1, B) = 88 blocks; latency hidden by R1-style per-chunk
//     prefetch + compiler pipelining of the now store-free loop body.

#define B_ 8
#define N_ 512
#define T_ 12
#define F_ 32
#define O_ 64
#define MT 1                    // m-splits per (b,t); block owns all 512 m-rows
#define NW 8                    // waves per block (512 threads)

typedef unsigned int uint_t;
typedef unsigned short ushort_t;
typedef _Float16 f16_t;
typedef _Float16 f16x4 __attribute__((ext_vector_type(4)));
typedef _Float16 f16x8 __attribute__((ext_vector_type(8)));
typedef float f32x4 __attribute__((ext_vector_type(4)));

__device__ __forceinline__ int xidx(int b, int n, int t, int f) {
    return ((b * N_ + n) * T_ + t) * F_ + f;
}
// load 8 consecutive fp32, convert to packed f16x8 (one MFMA A/B frag quarter)
__device__ __forceinline__ f16x8 load_frag8(const float* p) {
    float4 a = *reinterpret_cast<const float4*>(p);
    float4 b = *reinterpret_cast<const float4*>(p + 4);
    f16x8 r;
    r[0] = (f16_t)a.x; r[1] = (f16_t)a.y; r[2] = (f16_t)a.z; r[3] = (f16_t)a.w;
    r[4] = (f16_t)b.x; r[5] = (f16_t)b.y; r[6] = (f16_t)b.z; r[7] = (f16_t)b.w;
    return r;
}
union U2H4 { uint2 u; f16x4 h; };

// ---------------------------------------------------------------------------
// Permute one 512x512 fp32 slice into MFMA-lane-order fp16:
// dst halves h = ((mc*32 + nt)*256) + quad*64 + col*4 + j  <=  src[mc*16+quad*4+j][nt*16+col]
// so a consuming lane l=quad*16+col reads its 4 halves with ONE dwordx2.
__global__ __launch_bounds__(256)
void permute_kernel(const float* __restrict__ src, ushort_t* __restrict__ dst)
{
    __shared__ float Lp[16][516];
    const int tid = threadIdx.x;
    const int mc  = blockIdx.x;               // 0..31 row-chunk
    const int s   = blockIdx.y;               // slice (b*12+t for phase; 0 for adj)
    src += (size_t)s * N_ * N_ + (size_t)mc * 16 * N_;
    uint_t* dstu = (uint_t*)dst + (size_t)s * 131072 + (size_t)mc * 4096;

    #pragma unroll
    for (int k = 0; k < 32; ++k) {
        int idx = tid + 256 * k;              // 0..8191
        Lp[idx >> 9][idx & 511] = src[idx];
    }
    __syncthreads();
    #pragma unroll
    for (int k = 0; k < 16; ++k) {
        int u    = tid + 256 * k;             // u32 index 0..4095
        int nt   = u >> 7;
        int r    = u & 127;
        int quad = r >> 5;
        int cl   = (r >> 1) & 15;
        int m0   = quad * 4 + (r & 1) * 2;
        int n    = nt * 16 + cl;
        union { f16_t h[2]; uint_t i; } pk;
        pk.h[0] = (f16_t)Lp[m0][n];
        pk.h[1] = (f16_t)Lp[m0 + 1][n];
        dstu[u] = pk.i;
    }
}

// ---------------------------------------------------------------------------
// One Jacobi iteration step for all (b, t>=1); block = (0, t-1, b), 512 thr.
// FINAL=1: weight *= adj, Xp = X_t (same t), plain store to agg (no mask).
template <int FINAL>
__global__ __launch_bounds__(512)
void gcn_kernel(const float* __restrict__ x0,
                const float* __restrict__ xcur,
                float* __restrict__ dst,            // xnext or agg
                const ushort_t* __restrict__ phase_h,
                const ushort_t* __restrict__ adj_h,
                const float* __restrict__ mask)
{
    __shared__ float2 st[2][NW][16];

    const int tid  = threadIdx.x;
    const int w    = tid >> 6;
    const int l    = tid & 63;
    const int quad = l >> 4;
    const int col  = l & 15;
    const int t    = FINAL ? blockIdx.y : blockIdx.y + 1;
    const int b    = blockIdx.z;
    const int nt0  = w * 4;                  // wave owns n-tiles nt0..nt0+3
    const float inv_f = 0.17677669529663687f;

    const float* xs     = (FINAL && t == 0) ? x0 : xcur;     // X_t source
    const float* xp_src = FINAL ? xs : ((t == 1) ? x0 : xcur); // pred operand
    const int    tp     = FINAL ? t : t - 1;

    // score B-frags for this wave's 4 n-tiles (fixed across chunks)
    f16x8 bf[4];
    #pragma unroll
    for (int i = 0; i < 4; ++i)
        bf[i] = load_frag8(&xs[xidx(b, (nt0 + i) * 16 + col, t, quad * 8)]);

    f32x4 acc[4][2];
    #pragma unroll
    for (int i = 0; i < 4; ++i) {
        acc[i][0] = (f32x4){0.f, 0.f, 0.f, 0.f};
        acc[i][1] = (f32x4){0.f, 0.f, 0.f, 0.f};
    }

    const uint_t* phu = (const uint_t*)phase_h + (size_t)(b * T_ + t) * 131072;
    const uint_t* adu = (const uint_t*)adj_h;

    for (int c = 0; c < 512 / (MT * 16); ++c) {   // 32 chunks of 16 m-rows
        const int mb = c * 16;
        const int mc = c;                         // global chunk index

        // ---- issue ALL global loads for this chunk up front so their
        //      latency hides under the softmax shuffle chains + barrier ----
        f16x8 af = load_frag8(&xs[xidx(b, mb + col, t, quad * 8)]);

        U2H4 ph[4], aj[4];
        #pragma unroll
        for (int i = 0; i < 4; ++i) {
            ph[i].u = *(const uint2*)(phu + (size_t)mc * 4096 + (nt0 + i) * 128 + l * 2);
            if (FINAL)
                aj[i].u = *(const uint2*)(adu + (size_t)mc * 4096 + (nt0 + i) * 128 + l * 2);
        }
        // pred B-frags: Xp[m_local][f], K=16 layout k=quad*4+j
        f16x4 bp[2];
        #pragma unroll
        for (int ft = 0; ft < 2; ++ft)
            #pragma unroll
            for (int j = 0; j < 4; ++j)
                bp[ft][j] = (f16_t)xp_src[xidx(b, mb + quad * 4 + j, tp, ft * 16 + col)];

        // ---- scores: S[16 x 4*16] for this m-chunk ----
        f32x4 s4[4];
        #pragma unroll
        for (int i = 0; i < 4; ++i) {
            s4[i] = __builtin_amdgcn_mfma_f32_16x16x32_f16(
                        af, bf[i], (f32x4){0.f, 0.f, 0.f, 0.f}, 0, 0, 0);
        }
        // ---- wave-local softmax stats (rows m = quad*4+v, cols = 64 n) ----
        float mxw[4], sw[4], e[4][4];
        #pragma unroll
        for (int v = 0; v < 4; ++v) {
            #pragma unroll
            for (int i = 0; i < 4; ++i) s4[i][v] *= inv_f;
            mxw[v] = fmaxf(fmaxf(s4[0][v], s4[1][v]), fmaxf(s4[2][v], s4[3][v]));
        }
        #pragma unroll
        for (int d = 1; d < 16; d <<= 1)
            #pragma unroll
            for (int v = 0; v < 4; ++v)
                mxw[v] = fmaxf(mxw[v], __shfl_xor(mxw[v], d, 64));
        #pragma unroll
        for (int v = 0; v < 4; ++v) {
            #pragma unroll
            for (int i = 0; i < 4; ++i) e[i][v] = __expf(s4[i][v] - mxw[v]);
            sw[v] = (e[0][v] + e[1][v]) + (e[2][v] + e[3][v]);
        }
        #pragma unroll
        for (int d = 1; d < 16; d <<= 1)
            #pragma unroll
            for (int v = 0; v < 4; ++v)
                sw[v] += __shfl_xor(sw[v], d, 64);

        // ---- cross-wave combine via 2KB LDS (ping-pong, 1 barrier) ----
        const int buf = c & 1;
        if (col < 4) {
            float mv = (col == 0) ? mxw[0] : (col == 1) ? mxw[1] : (col == 2) ? mxw[2] : mxw[3];
            float sv = (col == 0) ? sw[0]  : (col == 1) ? sw[1]  : (col == 2) ? sw[2]  : sw[3];
            st[buf][w][quad * 4 + col] = make_float2(mv, sv);
        }
        __syncthreads();
        {
            const int row = l >> 2, wp = l & 3;
            float2 p0 = st[buf][2 * wp][row];
            float2 p1 = st[buf][2 * wp + 1][row];
            float M = fmaxf(p0.x, p1.x);
            float S = p0.y * __expf(p0.x - M) + p1.y * __expf(p1.x - M);
            #pragma unroll
            for (int d = 1; d < 4; d <<= 1) {
                float Mo = __shfl_xor(M, d, 64), So = __shfl_xor(S, d, 64);
                float Mn = fmaxf(M, Mo);
                S = S * __expf(M - Mn) + So * __expf(Mo - Mn);
                M = Mn;
            }
            #pragma unroll
            for (int v = 0; v < 4; ++v) {
                float Mr = __shfl(M, quad * 16 + v * 4, 64);
                float Sr = __shfl(S, quad * 16 + v * 4, 64);
                // beta = exp(local_max - global_max) * inv_f / global_sum
                mxw[v] = __expf(mxw[v] - Mr) * inv_f / Sr;   // reuse mxw as beta
            }
        }

        // ---- W = e*beta*phase(*adj), C-layout == A-layout of W^T; pred MFMA ----
        #pragma unroll
        for (int i = 0; i < 4; ++i) {
            f16x4 wf;
            if (FINAL) {
                #pragma unroll
                for (int v = 0; v < 4; ++v)
                    wf[v] = (f16_t)(e[i][v] * mxw[v] * (float)ph[i].h[v] * (float)aj[i].h[v]);
            } else {
                #pragma unroll
                for (int v = 0; v < 4; ++v)
                    wf[v] = (f16_t)(e[i][v] * mxw[v] * (float)ph[i].h[v]);
            }
            #pragma unroll
            for (int ft = 0; ft < 2; ++ft)
                acc[i][ft] = __builtin_amdgcn_mfma_f32_16x16x16f16(wf, bp[ft], acc[i][ft], 0, 0, 0);
        }
    }

    // ---- epilogue: exactly-once plain stores (no atomics, no memset) ----
    #pragma unroll
    for (int i = 0; i < 4; ++i) {
        #pragma unroll
        for (int v = 0; v < 4; ++v) {
            const int n = (nt0 + i) * 16 + quad * 4 + v;
            if (FINAL) {
                float* d0 = &dst[((b * T_ + t) * N_ + n) * F_ + col];
                d0[0]  = acc[i][0][v];
                d0[16] = acc[i][1][v];
            } else {
                const int i0 = xidx(b, n, t, col);
                const float mk  = mask[n];
                const float xc0 = xcur[i0];
                const float xc1 = xcur[i0 + 16];
                dst[i0]      = (mk != 0.f) ? xc0 : acc[i][0][v];
                dst[i0 + 16] = (mk != 0.f) ? xc1 : acc[i][1][v];
            }
        }
    }
}

// out[b,n,t,o] = relu(sum_f agg[b,t,n,f] * theta[f,o])
__global__ __launch_bounds__(256)
void proj_kernel(const float* __restrict__ agg, const float* __restrict__ theta,
                 float* __restrict__ out)
{
    __shared__ float th[F_ * O_];
    int tid = threadIdx.x;
    #pragma unroll
    for (int p = 0; p < 8; ++p) th[tid + 256 * p] = theta[tid + 256 * p];
    __syncthreads();
    int g  = blockIdx.x * 256 + tid;           // ((b*N+n)*T+t)*O+o
    int o  = g & 63;
    int r  = g >> 6;
    int tt = r % T_;
    int r2 = r / T_;
    int n  = r2 & 511;
    int b  = r2 >> 9;
    const float* a = &agg[((b * T_ + tt) * N_ + n) * F_];
    float s = 0.f;
    #pragma unroll
    for (int f = 0; f < F_; ++f) s += a[f] * th[f * O_ + o];
    out[g] = fmaxf(s, 0.f);
}

extern "C" void kernel_launch(void* const* d_in, const int* in_sizes, int n_in,
                              void* d_out, int out_size, void* d_ws, size_t ws_size,
                              hipStream_t stream)
{
    const float* x     = (const float*)d_in[0];
    const float* phase = (const float*)d_in[1];
    const float* adj   = (const float*)d_in[2];
    const float* mask  = (const float*)d_in[3];
    const float* theta = (const float*)d_in[4];
    float* out = (float*)d_out;

    const size_t XE = (size_t)B_ * N_ * T_ * F_;       // 1,572,864 floats
    float*    xA      = (float*)d_ws;                  //  6.3 MB
    float*    xB      = xA + XE;                       //  6.3 MB
    float*    agg     = xB + XE;                       //  6.3 MB
    ushort_t* phase_h = (ushort_t*)(agg + XE);         // 50.3 MB (96 slices, f16 permuted)
    ushort_t* adj_h   = phase_h + (size_t)96 * N_ * N_; // 0.5 MB

    permute_kernel<<<dim3(32, 96), 256, 0, stream>>>(phase, phase_h);
    permute_kernel<<<dim3(32, 1), 256, 0, stream>>>(adj, adj_h);

    const float* cur = x;
    float* bufs[2] = { xA, xB };
    for (int i = 0; i < T_ - 1; ++i) {                 // 11 Jacobi iterations
        float* nxt = bufs[i & 1];
        gcn_kernel<0><<<dim3(1, T_ - 1, B_), 512, 0, stream>>>(
            x, cur, nxt, phase_h, adj_h, mask);
        cur = nxt;
    }
    gcn_kernel<1><<<dim3(1, T_, B_), 512, 0, stream>>>(
        x, cur, agg, phase_h, adj_h, mask);
    proj_kernel<<<(B_ * N_ * T_ * O_) / 256, 256, 0, stream>>>(agg, theta, out);
}